// Round 8
// baseline (221.032 us; speedup 1.0000x reference)
//
#include <hip/hip_runtime.h>

using short8 = __attribute__((ext_vector_type(8))) short;
using f32x4  = __attribute__((ext_vector_type(4))) float;

#define HW   4800
#define MT   75            // 75 m-tiles of 64 (75*64 == 4800 exactly)
#define NPTS 1024
#define CDIM 256
#define NB   4
#define NROWS (NB*NPTS)    // 4096

// ---- workspace layout (bytes), total ~19.5 MiB ----
#define OFF_BITS 0
#define SZ_BITS  (NROWS*MT*8)
#define OFF_PART (OFF_BITS + SZ_BITS)
#define SZ_PART  (NROWS*MT*4*4)          // per (b,mt,n): bottom-4 f32 (n inner)
#define OFF_AG   (OFF_PART + SZ_PART)
#define SZ_AG    (NB*MT*16384*2)         // fragment-ordered RAW bf16 A-tiles
#define OFF_KDN  (OFF_AG + SZ_AG)
#define SZ_KDN   (NROWS*CDIM*2)
#define OFF_POS  (OFF_KDN + SZ_KDN)
#define SZ_POS   (NROWS*4)
#define OFF_INVK (OFF_POS + SZ_POS)
#define SZ_INVK  (NROWS*4)
#define OFF_NRM  (OFF_INVK + SZ_INVK)
#define SZ_NRM   (NB*HW*4)
#define WS_TOTAL (OFF_NRM + SZ_NRM)

__device__ inline unsigned short f2b(float v){
  unsigned int x; __builtin_memcpy(&x, &v, 4);
  x = x + 0x7fffu + ((x >> 16) & 1u);   // RNE
  return (unsigned short)(x >> 16);
}
__device__ inline int iclamp(int v, int lo, int hi){ return v < lo ? lo : (v > hi ? hi : v); }

__device__ inline void ins4(float v, float& a0, float& a1, float& a2, float& a3){
  if (v < a3){
    if (v < a2){ a3 = a2;
      if (v < a1){ a2 = a1;
        if (v < a0){ a1 = a0; a0 = v; } else a1 = v;
      } else a2 = v;
    } else a3 = v;
  }
}

__device__ inline void merge4(float& s0, float& s1, float& s2, float& s3, int off){
  float b0=__shfl_xor(s0,off), b1=__shfl_xor(s1,off), b2=__shfl_xor(s2,off), b3=__shfl_xor(s3,off);
  float c0=fminf(s0,b3), c1=fminf(s1,b2), c2=fminf(s2,b1), c3=fminf(s3,b0);
  float d0=fminf(c0,c2), e2=fmaxf(c0,c2), d1=fminf(c1,c3), e3=fmaxf(c1,c3);
  s0=fminf(d0,d1); s1=fmaxf(d0,d1); s2=fminf(e2,e3); s3=fmaxf(e2,e3);
}

// 4 nearest grid-cell indices (regular 8px lattice, 60x80) — no arrays (SSA only).
__device__ inline void nearest4(float px, float py, int& o0, int& o1, int& o2, int& o3){
  float aa = px*px + py*py;
  int ic = iclamp((int)floorf(px*0.125f - 0.5f) - 1, 0, 76);
  int jc = iclamp((int)floorf(py*0.125f - 0.5f) - 1, 0, 56);
  float v0=1e30f,v1=1e30f,v2=1e30f,v3=1e30f;
  int   i0=0,i1=0,i2=0,i3=0;
  for (int jj=jc; jj<jc+4; ++jj){
    for (int ii=ic; ii<ic+4; ++ii){
      float cx = (ii+0.5f)*8.f, cy = (jj+0.5f)*8.f;
      float q = (aa + (cx*cx + cy*cy)) - 2.f*(px*cx + py*cy);
      int m = jj*80 + ii;
      if (q < v3){
        if (q < v2){ v3=v2; i3=i2;
          if (q < v1){ v2=v1; i2=i1;
            if (q < v0){ v1=v0; i1=i0; v0=q; i0=m; } else { v1=q; i1=m; }
          } else { v2=q; i2=m; }
        } else { v3=q; i3=m; }
      }
    }
  }
  o0=i0; o1=i1; o2=i2; o3=i3;
}

// One wave per (b,n): raw bf16 kdn, invk, pos, exclusion bits. No private arrays.
__global__ __launch_bounds__(256) void prep_kernel(
    const float* __restrict__ kp1, const float* __restrict__ wkp1,
    const float* __restrict__ kdesc, const float* __restrict__ desc2,
    const float* __restrict__ homo,
    unsigned short* __restrict__ kdn, float* __restrict__ invk,
    float* __restrict__ pos, unsigned long long* __restrict__ bits)
{
  int wid  = blockIdx.x*4 + (threadIdx.x >> 6);
  int lane = threadIdx.x & 63;
  int b = wid >> 10;
  const float* kr = kdesc + (size_t)wid*CDIM + lane*4;
  float k0=kr[0], k1=kr[1], k2=kr[2], k3=kr[3];
  float ss = k0*k0 + k1*k1 + k2*k2 + k3*k3;
  for (int off=32; off>0; off>>=1) ss += __shfl_xor(ss, off);
  float ivk = 1.0f/sqrtf(ss + 1e-8f);
  {
    unsigned short* kw = kdn + (size_t)wid*CDIM + lane*4;
    kw[0]=f2b(k0); kw[1]=f2b(k1); kw[2]=f2b(k2); kw[3]=f2b(k3);
  }

  float px = wkp1[(size_t)wid*2+0]*0.125f - 0.5f;
  float py = wkp1[(size_t)wid*2+1]*0.125f - 0.5f;
  float x0f = floorf(px), y0f = floorf(py);
  float wx = px - x0f, wy = py - y0f;
  int x0 = iclamp((int)x0f, 0, 79);
  int x1 = x0+1 > 79 ? 79 : x0+1;
  int y0 = iclamp((int)y0f, 0, 59);
  int y1 = y0+1 > 59 ? 59 : y0+1;
  const float* dp = desc2 + (size_t)b*CDIM*HW;
  float wss = 0.f, wdot = 0.f;
  int cbase = lane*4;
  #pragma unroll
  for (int j=0; j<4; ++j){
    const float* p = dp + (size_t)(cbase+j)*HW;
    float d00=p[y0*80+x0], d01=p[y0*80+x1];
    float d10=p[y1*80+x0], d11=p[y1*80+x1];
    float top = d00*(1.f-wx) + d01*wx;
    float bot = d10*(1.f-wx) + d11*wx;
    float wv  = top*(1.f-wy) + bot*wy;
    wss += wv*wv;
    float kvj = (j==0) ? k0 : (j==1) ? k1 : (j==2) ? k2 : k3;
    wdot += wv*kvj;
  }
  for (int off=32; off>0; off>>=1){ wss += __shfl_xor(wss, off); wdot += __shfl_xor(wdot, off); }

  if (lane == 0){
    invk[wid] = ivk;
    float invw = 1.0f/sqrtf(wss + 1e-8f);
    pos[wid] = 2.f - 2.f*(wdot*ivk*invw);

    float qx = kp1[(size_t)wid*2+0], qy = kp1[(size_t)wid*2+1];
    int c10,c11,c12,c13; nearest4(qx, qy, c10,c11,c12,c13);
    float h0=homo[b*9+0], h1=homo[b*9+1], h2=homo[b*9+2];
    float h3=homo[b*9+3], h4=homo[b*9+4], h5=homo[b*9+5];
    float h6=homo[b*9+6], h7=homo[b*9+7], h8=homo[b*9+8];
    unsigned long long* brow = bits + (size_t)wid*MT;
    #define DO_CELL(M) { \
      int ii = (M) % 80, jj = (M) / 80; \
      float cx = (ii+0.5f)*8.f, cy = (jj+0.5f)*8.f; \
      float wz  = h6*cx + h7*cy + h8; \
      float wxp = (h0*cx + h1*cy + h2) / (wz + 1e-8f); \
      float wyp = (h3*cx + h4*cy + h5) / (wz + 1e-8f); \
      int d0,d1,d2,d3; nearest4(wxp, wyp, d0,d1,d2,d3); \
      brow[d0>>6] |= (1ull << (d0 & 63)); \
      brow[d1>>6] |= (1ull << (d1 & 63)); \
      brow[d2>>6] |= (1ull << (d2 & 63)); \
      brow[d3>>6] |= (1ull << (d3 & 63)); }
    DO_CELL(c10) DO_CELL(c11) DO_CELL(c12) DO_CELL(c13)
    #undef DO_CELL
  }
}

// Pure transpose+pack: block = (mt, cq, b), 1200 blocks. No private arrays.
__global__ __launch_bounds__(256) void d2t_kernel(const float* __restrict__ desc2,
                                                  unsigned short* __restrict__ a_glob,
                                                  float* __restrict__ nrm){
  int mt = blockIdx.x, cq = blockIdx.y, b = blockIdx.z;
  int t = threadIdx.x;
  int m_l = t & 63, og = t >> 6;
  const float* src = desc2 + (size_t)b*CDIM*HW + (size_t)mt*64 + m_l;
  unsigned short* dst = a_glob + (size_t)(b*MT + mt)*16384;
  int msub = m_l >> 4, nl = m_l & 15;
  __shared__ float red[4][64];
  float ssq = 0.f;
  #pragma unroll
  for (int o=0; o<2; ++o){
    int c0 = cq*64 + og*16 + o*8;
    short8 pk;
    #pragma unroll
    for (int j=0; j<8; ++j){
      float f = src[(size_t)(c0+j)*HW];
      ssq += f*f;
      pk[j] = (short)f2b(f);
    }
    int kf = c0 >> 5, qd = (c0 >> 3) & 3;
    *(short8*)(dst + (((msub*8 + kf)*64 + qd*16 + nl) << 3)) = pk;
  }
  red[og][m_l] = ssq;
  __syncthreads();
  if (t < 64) atomicAdd(nrm + (size_t)b*HW + mt*64 + t,
                        red[0][t]+red[1][t]+red[2][t]+red[3][t]);
}

// GEMM+select. ALL fragments in named SSA variables — no per-thread arrays
// (arrays of short8 failed promote-alloca -> lived in SCRATCH -> 100us floor).
__global__ __launch_bounds__(256, 2) void gemm_select(
    const unsigned short* __restrict__ kdn, const unsigned short* __restrict__ a_glob,
    const unsigned long long* __restrict__ bits, const float* __restrict__ invk,
    const float* __restrict__ nrm, float* __restrict__ part)
{
  int idx = blockIdx.x;
  int nh  = idx / 300;
  int rem = idx - nh*300;
  int b   = rem / MT;
  int mt  = rem - b*MT;
  int t = threadIdx.x;
  int wave = t >> 6, lane = t & 63;
  int quad = lane >> 4, nl = lane & 15;

  __shared__ __align__(16) unsigned short ashare[16384];  // 32 KB fragment-ordered
  __shared__ float snrm[64];

  int nP = nh*128 + wave*32 + nl;
  int nQ = nP + 16;
  int rP = b*NPTS + nP, rQ = b*NPTS + nQ;
  const unsigned short* kbP = kdn + (size_t)rP*CDIM + quad*8;
  const unsigned short* kbQ = kdn + (size_t)rQ*CDIM + quad*8;
  short8 bP0 = *(const short8*)(kbP +   0), bQ0 = *(const short8*)(kbQ +   0);
  short8 bP1 = *(const short8*)(kbP +  32), bQ1 = *(const short8*)(kbQ +  32);
  short8 bP2 = *(const short8*)(kbP +  64), bQ2 = *(const short8*)(kbQ +  64);
  short8 bP3 = *(const short8*)(kbP +  96), bQ3 = *(const short8*)(kbQ +  96);
  short8 bP4 = *(const short8*)(kbP + 128), bQ4 = *(const short8*)(kbQ + 128);
  short8 bP5 = *(const short8*)(kbP + 160), bQ5 = *(const short8*)(kbQ + 160);
  short8 bP6 = *(const short8*)(kbP + 192), bQ6 = *(const short8*)(kbQ + 192);
  short8 bP7 = *(const short8*)(kbP + 224), bQ7 = *(const short8*)(kbQ + 224);
  float ivkP = invk[rP], ivkQ = invk[rQ];
  unsigned long long wP = bits[(size_t)rP*MT + mt];
  unsigned long long wQ = bits[(size_t)rQ*MT + mt];

  // stage A tile: 8 x (coalesced 16B load -> ds_write_b128), named temporaries
  {
    const unsigned short* ag = a_glob + (size_t)(b*MT + mt)*16384;
    short8 t0 = *(const short8*)(ag + ((0*256 + t) << 3));
    short8 t1 = *(const short8*)(ag + ((1*256 + t) << 3));
    short8 t2 = *(const short8*)(ag + ((2*256 + t) << 3));
    short8 t3 = *(const short8*)(ag + ((3*256 + t) << 3));
    short8 t4 = *(const short8*)(ag + ((4*256 + t) << 3));
    short8 t5 = *(const short8*)(ag + ((5*256 + t) << 3));
    short8 t6 = *(const short8*)(ag + ((6*256 + t) << 3));
    short8 t7 = *(const short8*)(ag + ((7*256 + t) << 3));
    *(short8*)(ashare + ((0*256 + t) << 3)) = t0;
    *(short8*)(ashare + ((1*256 + t) << 3)) = t1;
    *(short8*)(ashare + ((2*256 + t) << 3)) = t2;
    *(short8*)(ashare + ((3*256 + t) << 3)) = t3;
    *(short8*)(ashare + ((4*256 + t) << 3)) = t4;
    *(short8*)(ashare + ((5*256 + t) << 3)) = t5;
    *(short8*)(ashare + ((6*256 + t) << 3)) = t6;
    *(short8*)(ashare + ((7*256 + t) << 3)) = t7;
    if (t < 64) snrm[t] = rsqrtf(nrm[(size_t)b*HW + mt*64 + t] + 1e-8f);
  }
  __syncthreads();

  float p0=1e30f,p1=1e30f,p2=1e30f,p3=1e30f;
  float q0=1e30f,q1=1e30f,q2=1e30f,q3=1e30f;
  #pragma unroll
  for (int msub=0; msub<4; ++msub){
    f32x4 accP = {0.f,0.f,0.f,0.f}, accQ = {0.f,0.f,0.f,0.f};
    #define KSTEP(KF, BP, BQ) { \
      short8 a = *(short8*)(ashare + (((msub*8 + (KF))*64 + lane) << 3)); \
      accP = __builtin_amdgcn_mfma_f32_16x16x32_bf16(a, BP, accP, 0, 0, 0); \
      accQ = __builtin_amdgcn_mfma_f32_16x16x32_bf16(a, BQ, accQ, 0, 0, 0); }
    KSTEP(0,bP0,bQ0) KSTEP(1,bP1,bQ1) KSTEP(2,bP2,bQ2) KSTEP(3,bP3,bQ3)
    KSTEP(4,bP4,bQ4) KSTEP(5,bP5,bQ5) KSTEP(6,bP6,bQ6) KSTEP(7,bP7,bQ7)
    #undef KSTEP
    #pragma unroll
    for (int rr=0; rr<4; ++rr){
      int ml2 = msub*16 + quad*4 + rr;   // C/D: col=lane&15 (=n), row=quad*4+rr
      float sn = snrm[ml2];
      float vP = 2.f - 2.f*accP[rr]*sn*ivkP;
      float vQ = 2.f - 2.f*accQ[rr]*sn*ivkQ;
      if (!((wP >> ml2) & 1ull)) ins4(vP, p0,p1,p2,p3);
      if (!((wQ >> ml2) & 1ull)) ins4(vQ, q0,q1,q2,q3);
    }
  }
  merge4(p0,p1,p2,p3,16); merge4(p0,p1,p2,p3,32);
  merge4(q0,q1,q2,q3,16); merge4(q0,q1,q2,q3,32);
  if (lane < 16){
    *(f32x4*)(part + ((size_t)(b*MT + mt)*NPTS + nP)*4) = (f32x4){p0,p1,p2,p3};
    *(f32x4*)(part + ((size_t)(b*MT + mt)*NPTS + nQ)*4) = (f32x4){q0,q1,q2,q3};
  }
}

// One wave per (b,n): reduce bottom-4 over 75 m-tiles, hinge, atomic into d_out.
__global__ __launch_bounds__(1024) void finalize(const float* __restrict__ part,
                                                 const float* __restrict__ pos,
                                                 float* __restrict__ out){
  int wave = threadIdx.x >> 6, lane = threadIdx.x & 63;
  int row = blockIdx.x*16 + wave;
  int b = row >> 10, n = row & 1023;
  float a0=1e30f, a1=1e30f, a2=1e30f, a3=1e30f;
  {
    const f32x4 v = *(const f32x4*)(part + ((size_t)(b*MT + lane)*NPTS + n)*4);
    ins4(v[0],a0,a1,a2,a3); ins4(v[1],a0,a1,a2,a3);
    ins4(v[2],a0,a1,a2,a3); ins4(v[3],a0,a1,a2,a3);
  }
  if (lane < MT-64){
    const f32x4 v = *(const f32x4*)(part + ((size_t)(b*MT + 64 + lane)*NPTS + n)*4);
    ins4(v[0],a0,a1,a2,a3); ins4(v[1],a0,a1,a2,a3);
    ins4(v[2],a0,a1,a2,a3); ins4(v[3],a0,a1,a2,a3);
  }
  #pragma unroll
  for (int off=1; off<64; off<<=1) merge4(a0,a1,a2,a3,off);

  __shared__ float ls[16];
  if (lane == 0){
    float p = pos[row];
    ls[wave] = fmaxf(p-a0+1.f,0.f) + fmaxf(p-a1+1.f,0.f)
             + fmaxf(p-a2+1.f,0.f) + fmaxf(p-a3+1.f,0.f);
  }
  __syncthreads();
  if (threadIdx.x == 0){
    float s = 0.f;
    #pragma unroll
    for (int i=0; i<16; ++i) s += ls[i];
    atomicAdd(out, s * (1.0f/16384.0f));
  }
}

__global__ void ws_too_small(float* out){ out[0] = -12345.0f; }

extern "C" void kernel_launch(void* const* d_in, const int* in_sizes, int n_in,
                              void* d_out, int out_size, void* d_ws, size_t ws_size,
                              hipStream_t stream) {
  (void)in_sizes; (void)n_in; (void)out_size;
  if (ws_size < (size_t)WS_TOTAL){
    ws_too_small<<<1, 1, 0, stream>>>((float*)d_out);
    return;
  }
  const float* kp1   = (const float*)d_in[0];
  const float* wkp1  = (const float*)d_in[1];
  const float* kdesc = (const float*)d_in[2];
  const float* desc2 = (const float*)d_in[3];
  const float* homo  = (const float*)d_in[4];

  char* ws = (char*)d_ws;
  unsigned long long* bits = (unsigned long long*)(ws + OFF_BITS);
  float*          part   = (float*)(ws + OFF_PART);
  unsigned short* a_glob = (unsigned short*)(ws + OFF_AG);
  unsigned short* kdn    = (unsigned short*)(ws + OFF_KDN);
  float*          pos    = (float*)(ws + OFF_POS);
  float*          invk   = (float*)(ws + OFF_INVK);
  float*          nrm    = (float*)(ws + OFF_NRM);

  hipMemsetAsync(bits, 0, SZ_BITS, stream);
  hipMemsetAsync(nrm, 0, SZ_NRM, stream);
  hipMemsetAsync(d_out, 0, 4, stream);

  prep_kernel<<<1024, 256, 0, stream>>>(kp1, wkp1, kdesc, desc2, homo, kdn, invk, pos, bits);
  d2t_kernel<<<dim3(MT, 4, NB), 256, 0, stream>>>(desc2, a_glob, nrm);
  gemm_select<<<2400, 256, 0, stream>>>(kdn, a_glob, bits, invk, nrm, part);
  finalize<<<256, 1024, 0, stream>>>(part, pos, (float*)d_out);
}

// Round 9
// 199.561 us; speedup vs baseline: 1.1076x; 1.1076x over previous
//
#include <hip/hip_runtime.h>

using short8  = __attribute__((ext_vector_type(8))) short;
using short4v = __attribute__((ext_vector_type(4))) short;
using f32x4   = __attribute__((ext_vector_type(4))) float;

#define HW   4800
#define MT   75            // 75 m-tiles of 64
#define NPTS 1024
#define CDIM 256
#define NB   4
#define NROWS 4096

// ---- workspace layout (bytes), total ~19.65 MiB ----
#define OFF_BITS 0
#define SZ_BITS  (NROWS*MT*8)            // u64 exclusion mask, FULLY written by prep
#define OFF_PART (OFF_BITS + SZ_BITS)
#define SZ_PART  (NROWS*MT*4*4)          // (b,n,mt) bottom-4 f32
#define OFF_AG   (OFF_PART + SZ_PART)
#define SZ_AG    (NB*MT*16384*2)         // fragment-ordered raw bf16 A-tiles
#define OFF_KDNF (OFF_AG + SZ_AG)
#define SZ_KDNF  (NB*64*4096*2)          // fragment-ordered raw bf16 B (kdesc)
#define OFF_POS  (OFF_KDNF + SZ_KDNF)
#define SZ_POS   (NROWS*4)
#define OFF_INVK (OFF_POS + SZ_POS)
#define SZ_INVK  (NROWS*4)
#define OFF_NRM4 (OFF_INVK + SZ_INVK)
#define SZ_NRM4  (4*NB*HW*4)             // 4 partial ssq planes (always fully written)
#define OFF_ACC  (OFF_NRM4 + SZ_NRM4)    // f32 acc + u32 counter
#define WS_TOTAL (OFF_ACC + 8)

__device__ inline unsigned short f2b(float v){
  unsigned int x; __builtin_memcpy(&x, &v, 4);
  x = x + 0x7fffu + ((x >> 16) & 1u);   // RNE
  return (unsigned short)(x >> 16);
}
__device__ inline int iclamp(int v, int lo, int hi){ return v < lo ? lo : (v > hi ? hi : v); }

__device__ inline void ins4(float v, float& a0, float& a1, float& a2, float& a3){
  if (v < a3){
    if (v < a2){ a3 = a2;
      if (v < a1){ a2 = a1;
        if (v < a0){ a1 = a0; a0 = v; } else a1 = v;
      } else a2 = v;
    } else a3 = v;
  }
}

__device__ inline void merge4(float& s0, float& s1, float& s2, float& s3, int off){
  float b0=__shfl_xor(s0,off), b1=__shfl_xor(s1,off), b2=__shfl_xor(s2,off), b3=__shfl_xor(s3,off);
  float c0=fminf(s0,b3), c1=fminf(s1,b2), c2=fminf(s2,b1), c3=fminf(s3,b0);
  float d0=fminf(c0,c2), e2=fmaxf(c0,c2), d1=fminf(c1,c3), e3=fmaxf(c1,c3);
  s0=fminf(d0,d1); s1=fmaxf(d0,d1); s2=fminf(e2,e3); s3=fmaxf(e2,e3);
}

// 4 nearest grid-cell indices (regular 8px lattice, 60x80), SSA only.
__device__ inline void nearest4(float px, float py, int& o0, int& o1, int& o2, int& o3){
  float aa = px*px + py*py;
  int ic = iclamp((int)floorf(px*0.125f - 0.5f) - 1, 0, 76);
  int jc = iclamp((int)floorf(py*0.125f - 0.5f) - 1, 0, 56);
  float v0=1e30f,v1=1e30f,v2=1e30f,v3=1e30f;
  int   i0=0,i1=0,i2=0,i3=0;
  for (int jj=jc; jj<jc+4; ++jj){
    for (int ii=ic; ii<ic+4; ++ii){
      float cx = (ii+0.5f)*8.f, cy = (jj+0.5f)*8.f;
      float q = (aa + (cx*cx + cy*cy)) - 2.f*(px*cx + py*cy);
      int m = jj*80 + ii;
      if (q < v3){
        if (q < v2){ v3=v2; i3=i2;
          if (q < v1){ v2=v1; i2=i1;
            if (q < v0){ v1=v0; i1=i0; v0=q; i0=m; } else { v1=q; i1=m; }
          } else { v2=q; i2=m; }
        } else { v3=q; i3=m; }
      }
    }
  }
  o0=i0; o1=i1; o2=i2; o3=i3;
}

// Fused: blocks [0,1200) = d2t transpose/pack; blocks [1200,2224) = prep.
__global__ __launch_bounds__(256) void prep_d2t(
    const float* __restrict__ kp1, const float* __restrict__ wkp1,
    const float* __restrict__ kdesc, const float* __restrict__ desc2,
    const float* __restrict__ homo,
    unsigned short* __restrict__ kdnf, unsigned short* __restrict__ a_glob,
    float* __restrict__ nrm4, float* __restrict__ invk, float* __restrict__ pos,
    unsigned long long* __restrict__ bits, float* __restrict__ acc,
    unsigned int* __restrict__ cnt)
{
  int bx = blockIdx.x;
  if (bx < 1200){
    // ---- d2t: (mt, cq, b) transpose + pack + partial row-ssq ----
    int mt = bx % 75;
    int rest = bx / 75;
    int cq = rest & 3, b = rest >> 2;
    int t = threadIdx.x;
    int m_l = t & 63, og = t >> 6;
    const float* src = desc2 + (size_t)b*CDIM*HW + (size_t)mt*64 + m_l;
    unsigned short* dst = a_glob + (size_t)(b*MT + mt)*16384;
    int msub = m_l >> 4, nl = m_l & 15;
    __shared__ float red[4][64];
    float ssq = 0.f;
    #pragma unroll
    for (int o=0; o<2; ++o){
      int c0 = cq*64 + og*16 + o*8;
      short8 pk;
      #pragma unroll
      for (int j=0; j<8; ++j){
        float f = src[(size_t)(c0+j)*HW];
        ssq += f*f;
        pk[j] = (short)f2b(f);
      }
      int kf = c0 >> 5, qd = (c0 >> 3) & 3;
      *(short8*)(dst + (((msub*8 + kf)*64 + qd*16 + nl) << 3)) = pk;
    }
    red[og][m_l] = ssq;
    __syncthreads();
    if (t < 64)
      nrm4[(size_t)cq*(NB*HW) + (size_t)b*HW + mt*64 + t] =
        red[0][t]+red[1][t]+red[2][t]+red[3][t];
    return;
  }

  // ---- prep: one wave per (b,n) ----
  int pb = bx - 1200;
  if (pb == 0 && threadIdx.x == 0){ acc[0] = 0.f; cnt[0] = 0u; }
  int wid  = pb*4 + (threadIdx.x >> 6);
  int lane = threadIdx.x & 63;
  int b = wid >> 10;
  const float* kr = kdesc + (size_t)wid*CDIM + lane*4;
  float k0=kr[0], k1=kr[1], k2=kr[2], k3=kr[3];
  float ss = k0*k0 + k1*k1 + k2*k2 + k3*k3;
  for (int off=32; off>0; off>>=1) ss += __shfl_xor(ss, off);
  float ivk = 1.0f/sqrtf(ss + 1e-8f);

  // raw bf16 B-fragments in MFMA fragment order (c = 4*lane .. +3)
  {
    int n = wid & 1023;
    int nt = n >> 4, nl2 = n & 15;
    int kf = lane >> 3, quad = (lane >> 1) & 3, j = (lane & 1)*4;
    short4v pk; pk[0]=(short)f2b(k0); pk[1]=(short)f2b(k1); pk[2]=(short)f2b(k2); pk[3]=(short)f2b(k3);
    *(short4v*)(kdnf + ((size_t)(b*64 + nt) << 12) + ((kf*64 + quad*16 + nl2) << 3) + j) = pk;
  }

  // bilinear sample at w_kp1/8 - 0.5
  float px = wkp1[(size_t)wid*2+0]*0.125f - 0.5f;
  float py = wkp1[(size_t)wid*2+1]*0.125f - 0.5f;
  float x0f = floorf(px), y0f = floorf(py);
  float wx = px - x0f, wy = py - y0f;
  int x0 = iclamp((int)x0f, 0, 79);
  int x1 = x0+1 > 79 ? 79 : x0+1;
  int y0 = iclamp((int)y0f, 0, 59);
  int y1 = y0+1 > 59 ? 59 : y0+1;
  const float* dp = desc2 + (size_t)b*CDIM*HW;
  float wss = 0.f, wdot = 0.f;
  int cbase = lane*4;
  #pragma unroll
  for (int j=0; j<4; ++j){
    const float* p = dp + (size_t)(cbase+j)*HW;
    float d00=p[y0*80+x0], d01=p[y0*80+x1];
    float d10=p[y1*80+x0], d11=p[y1*80+x1];
    float top = d00*(1.f-wx) + d01*wx;
    float bot = d10*(1.f-wx) + d11*wx;
    float wv  = top*(1.f-wy) + bot*wy;
    wss += wv*wv;
    float kvj = (j==0) ? k0 : (j==1) ? k1 : (j==2) ? k2 : k3;
    wdot += wv*kvj;
  }
  for (int off=32; off>0; off>>=1){ wss += __shfl_xor(wss, off); wdot += __shfl_xor(wdot, off); }
  if (lane == 0){
    invk[wid] = ivk;
    float invw = 1.0f/sqrtf(wss + 1e-8f);
    pos[wid] = 2.f - 2.f*(wdot*ivk*invw);
  }

  // geometry: lanes 0..3 each warp one of the 4 nearest cells; every lane
  // then composes its own exclusion word(s) -> bits row fully written, no memset.
  float qx = kp1[(size_t)wid*2+0], qy = kp1[(size_t)wid*2+1];
  int c10,c11,c12,c13; nearest4(qx, qy, c10,c11,c12,c13);
  int myc = (lane==1) ? c11 : (lane==2) ? c12 : (lane==3) ? c13 : c10;
  float h0=homo[b*9+0], h1=homo[b*9+1], h2=homo[b*9+2];
  float h3=homo[b*9+3], h4=homo[b*9+4], h5=homo[b*9+5];
  float h6=homo[b*9+6], h7=homo[b*9+7], h8=homo[b*9+8];
  int d0=0,d1=0,d2=0,d3=0;
  if (lane < 4){
    int ii = myc % 80, jj = myc / 80;
    float cx = (ii+0.5f)*8.f, cy = (jj+0.5f)*8.f;
    float wz  = h6*cx + h7*cy + h8;
    float wxp = (h0*cx + h1*cy + h2) / (wz + 1e-8f);
    float wyp = (h3*cx + h4*cy + h5) / (wz + 1e-8f);
    nearest4(wxp, wyp, d0,d1,d2,d3);
  }
  unsigned long long w1 = 0ull, w2 = 0ull;
  int l64 = lane + 64;
  #pragma unroll
  for (int s=0; s<4; ++s){
    int e0=__shfl(d0,s), e1=__shfl(d1,s), e2=__shfl(d2,s), e3=__shfl(d3,s);
    #define ADDB(E) { if (((E)>>6)==lane) w1 |= 1ull<<((E)&63); \
                      if (((E)>>6)==l64)  w2 |= 1ull<<((E)&63); }
    ADDB(e0) ADDB(e1) ADDB(e2) ADDB(e3)
    #undef ADDB
  }
  unsigned long long* brow = bits + (size_t)wid*MT;
  brow[lane] = w1;
  if (lane < MT-64) brow[64+lane] = w2;
}

// GEMM+select. Block = one (tile=b*75+mt, nh of 64 n), XCD-pinned: all 16
// nh-blocks of a tile share blockIdx%8. Wave = 16n x 64m: 8 B-frags (32 VGPR,
// no spill by construction) from coalesced global kdnf; A via LDS.
__global__ __launch_bounds__(256) void gemm_select(
    const unsigned short* __restrict__ kdnf, const unsigned short* __restrict__ a_glob,
    const unsigned long long* __restrict__ bits, const float* __restrict__ invk,
    const float* __restrict__ nrm4, float* __restrict__ part)
{
  int idx = blockIdx.x;
  int x = idx & 7, r = idx >> 3;
  int t_loc = r >> 4, nh = r & 15;
  int tile = t_loc*8 + x;
  if (tile >= 300) return;
  int b = tile / 75, mt = tile - b*75;
  int t = threadIdx.x;
  int wave = t >> 6, lane = t & 63;
  int quad = lane >> 4, nl = lane & 15;

  __shared__ __align__(16) unsigned short ashare[16384];  // 32 KB
  __shared__ float snrm[64];

  int n = nh*64 + wave*16 + nl;
  int row = b*NPTS + n;
  float ivk = invk[row];
  unsigned long long w64 = bits[(size_t)row*MT + mt];

  const unsigned short* kb = kdnf + ((size_t)(b*64 + nh*4 + wave) << 12);
  short8 bf0 = *(const short8*)(kb + ((0*64 + lane)<<3));
  short8 bf1 = *(const short8*)(kb + ((1*64 + lane)<<3));
  short8 bf2 = *(const short8*)(kb + ((2*64 + lane)<<3));
  short8 bf3 = *(const short8*)(kb + ((3*64 + lane)<<3));
  short8 bf4 = *(const short8*)(kb + ((4*64 + lane)<<3));
  short8 bf5 = *(const short8*)(kb + ((5*64 + lane)<<3));
  short8 bf6 = *(const short8*)(kb + ((6*64 + lane)<<3));
  short8 bf7 = *(const short8*)(kb + ((7*64 + lane)<<3));

  {
    const unsigned short* ag = a_glob + (size_t)tile*16384;
    short8 t0 = *(const short8*)(ag + ((0*256 + t) << 3));
    short8 t1 = *(const short8*)(ag + ((1*256 + t) << 3));
    short8 t2 = *(const short8*)(ag + ((2*256 + t) << 3));
    short8 t3 = *(const short8*)(ag + ((3*256 + t) << 3));
    short8 t4 = *(const short8*)(ag + ((4*256 + t) << 3));
    short8 t5 = *(const short8*)(ag + ((5*256 + t) << 3));
    short8 t6 = *(const short8*)(ag + ((6*256 + t) << 3));
    short8 t7 = *(const short8*)(ag + ((7*256 + t) << 3));
    *(short8*)(ashare + ((0*256 + t) << 3)) = t0;
    *(short8*)(ashare + ((1*256 + t) << 3)) = t1;
    *(short8*)(ashare + ((2*256 + t) << 3)) = t2;
    *(short8*)(ashare + ((3*256 + t) << 3)) = t3;
    *(short8*)(ashare + ((4*256 + t) << 3)) = t4;
    *(short8*)(ashare + ((5*256 + t) << 3)) = t5;
    *(short8*)(ashare + ((6*256 + t) << 3)) = t6;
    *(short8*)(ashare + ((7*256 + t) << 3)) = t7;
    if (t < 64){
      size_t o = (size_t)b*HW + mt*64 + t;
      snrm[t] = rsqrtf(nrm4[o] + nrm4[(size_t)NB*HW + o] +
                       nrm4[2*(size_t)NB*HW + o] + nrm4[3*(size_t)NB*HW + o] + 1e-8f);
    }
  }
  __syncthreads();

  float s0=1e30f,s1=1e30f,s2=1e30f,s3=1e30f;
  #pragma unroll
  for (int msub=0; msub<4; ++msub){
    f32x4 accA = {0.f,0.f,0.f,0.f}, accB = {0.f,0.f,0.f,0.f};
    #define KSTEP(KF, ACC, BF) { \
      short8 a = *(short8*)(ashare + (((msub*8 + (KF))*64 + lane) << 3)); \
      ACC = __builtin_amdgcn_mfma_f32_16x16x32_bf16(a, BF, ACC, 0, 0, 0); }
    KSTEP(0,accA,bf0) KSTEP(1,accA,bf1) KSTEP(2,accA,bf2) KSTEP(3,accA,bf3)
    KSTEP(4,accB,bf4) KSTEP(5,accB,bf5) KSTEP(6,accB,bf6) KSTEP(7,accB,bf7)
    #undef KSTEP
    #pragma unroll
    for (int rr=0; rr<4; ++rr){
      int ml2 = msub*16 + quad*4 + rr;   // C/D: col=lane&15 (=n), row=quad*4+rr
      float val = 2.f - 2.f*(accA[rr]+accB[rr])*snrm[ml2]*ivk;
      if (!((w64 >> ml2) & 1ull)) ins4(val, s0,s1,s2,s3);
    }
  }
  merge4(s0,s1,s2,s3,16);
  merge4(s0,s1,s2,s3,32);
  if (lane < 16)
    *(f32x4*)(part + ((size_t)row*MT + mt)*4) = (f32x4){s0,s1,s2,s3};
}

// One wave per (b,n): coalesced (b,n,mt) reads, hinge, self-electing drain.
__global__ __launch_bounds__(1024) void finalize(const float* __restrict__ part,
                                                 const float* __restrict__ pos,
                                                 float* __restrict__ acc,
                                                 unsigned int* __restrict__ cnt,
                                                 float* __restrict__ out){
  int wave = threadIdx.x >> 6, lane = threadIdx.x & 63;
  int row = blockIdx.x*16 + wave;
  const float* base = part + (size_t)row*MT*4;
  float a0=1e30f, a1=1e30f, a2=1e30f, a3=1e30f;
  {
    const f32x4 v = *(const f32x4*)(base + lane*4);
    ins4(v[0],a0,a1,a2,a3); ins4(v[1],a0,a1,a2,a3);
    ins4(v[2],a0,a1,a2,a3); ins4(v[3],a0,a1,a2,a3);
  }
  if (lane < MT-64){
    const f32x4 v = *(const f32x4*)(base + (64+lane)*4);
    ins4(v[0],a0,a1,a2,a3); ins4(v[1],a0,a1,a2,a3);
    ins4(v[2],a0,a1,a2,a3); ins4(v[3],a0,a1,a2,a3);
  }
  #pragma unroll
  for (int off=1; off<64; off<<=1) merge4(a0,a1,a2,a3,off);

  __shared__ float ls[16];
  if (lane == 0){
    float p = pos[row];
    ls[wave] = fmaxf(p-a0+1.f,0.f) + fmaxf(p-a1+1.f,0.f)
             + fmaxf(p-a2+1.f,0.f) + fmaxf(p-a3+1.f,0.f);
  }
  __syncthreads();
  if (threadIdx.x == 0){
    float s = 0.f;
    #pragma unroll
    for (int i=0; i<16; ++i) s += ls[i];
    atomicAdd(acc, s);
    __threadfence();
    unsigned int c = atomicAdd(cnt, 1u);
    if (c == 255u){
      float tot = atomicAdd(acc, 0.0f);   // coherent read-after-all-adds
      out[0] = tot * (1.0f/16384.0f);
    }
  }
}

__global__ void ws_too_small(float* out){ out[0] = -12345.0f; }

extern "C" void kernel_launch(void* const* d_in, const int* in_sizes, int n_in,
                              void* d_out, int out_size, void* d_ws, size_t ws_size,
                              hipStream_t stream) {
  (void)in_sizes; (void)n_in; (void)out_size;
  if (ws_size < (size_t)WS_TOTAL){
    ws_too_small<<<1, 1, 0, stream>>>((float*)d_out);
    return;
  }
  const float* kp1   = (const float*)d_in[0];
  const float* wkp1  = (const float*)d_in[1];
  const float* kdesc = (const float*)d_in[2];
  const float* desc2 = (const float*)d_in[3];
  const float* homo  = (const float*)d_in[4];

  char* ws = (char*)d_ws;
  unsigned long long* bits = (unsigned long long*)(ws + OFF_BITS);
  float*          part   = (float*)(ws + OFF_PART);
  unsigned short* a_glob = (unsigned short*)(ws + OFF_AG);
  unsigned short* kdnf   = (unsigned short*)(ws + OFF_KDNF);
  float*          pos    = (float*)(ws + OFF_POS);
  float*          invk   = (float*)(ws + OFF_INVK);
  float*          nrm4   = (float*)(ws + OFF_NRM4);
  float*          acc    = (float*)(ws + OFF_ACC);
  unsigned int*   cnt    = (unsigned int*)(ws + OFF_ACC + 4);

  prep_d2t<<<2224, 256, 0, stream>>>(kp1, wkp1, kdesc, desc2, homo,
                                     kdnf, a_glob, nrm4, invk, pos, bits, acc, cnt);
  gemm_select<<<4864, 256, 0, stream>>>(kdnf, a_glob, bits, invk, nrm4, part);
  finalize<<<256, 1024, 0, stream>>>(part, pos, acc, cnt, (float*)d_out);
}